// Round 8
// baseline (285.231 us; speedup 1.0000x reference)
//
#include <hip/hip_runtime.h>

// VectorQuantizerEMA: N=16384, K=1024, D=256.
// Outputs (f32, concat): recons [N,D] | gamma [N,K] | new_centroids [K,D]
// R8: fully fused dist+softmax+scatter kernel. z quantized in-kernel to LDS;
// two-pass online softmax with MFMA recompute (dist never hits HBM).
// i8 3-term dot (hh + (hl+lh)/256), mfma_i32_32x32x32_i8, XOR chunk swizzle.

#define DECAY 0.95f
#define OMD   0.05f
#define EPSV  1e-5f

using i32x4  = __attribute__((ext_vector_type(4))) int;
using i32x16 = __attribute__((ext_vector_type(16))) int;

typedef __attribute__((address_space(3))) unsigned int       lds_uint;
typedef const __attribute__((address_space(1))) unsigned int glb_uint;

__device__ __forceinline__ void gload16(const void* g, const void* l) {
  __builtin_amdgcn_global_load_lds((glb_uint*)(unsigned long long)g,
                                   (lds_uint*)(unsigned int)(unsigned long long)l,
                                   16, 0, 0);
}

// ---------------------------------------------------------------- prep
// bid 0..127  : cent int8 hi/lo quantize + sc + csq (8 rows/block)
// bid 128..384: zero dw+counts
// bid 385     : S = sum(ema_cs)
__global__ __launch_bounds__(256) void prep(const float* __restrict__ cent,
                                            const float* __restrict__ ema_cs,
                                            signed char* __restrict__ c8,
                                            float* __restrict__ sc,
                                            float* __restrict__ csq,
                                            float* __restrict__ dwzero,
                                            float* __restrict__ S) {
  const int bid = blockIdx.x;
  const int t   = threadIdx.x;
  if (bid < 128) {
    const int r  = bid * 8 + (t >> 5);
    const int d0 = (t & 31) * 8;
    const float4 a = *(const float4*)&cent[(size_t)r * 256 + d0];
    const float4 b = *(const float4*)&cent[(size_t)r * 256 + d0 + 4];
    float f[8] = {a.x, a.y, a.z, a.w, b.x, b.y, b.z, b.w};
    float am = 0.f, ssq = 0.f;
#pragma unroll
    for (int j = 0; j < 8; ++j) { am = fmaxf(am, fabsf(f[j])); ssq += f[j] * f[j]; }
#pragma unroll
    for (int off = 16; off; off >>= 1) {
      am  = fmaxf(am, __shfl_down(am, off, 32));
      ssq += __shfl_down(ssq, off, 32);
    }
    am = __shfl(am, 0, 32);
    const float s  = fmaxf(am, 1e-6f) * (1.0f / 127.0f);
    const float rs = 1.0f / s;
    union { signed char c[8]; uint2 u; } H, L;
#pragma unroll
    for (int j = 0; j < 8; ++j) {
      float q = rintf(f[j] * rs);
      q = fminf(fmaxf(q, -127.f), 127.f);
      H.c[j] = (signed char)(int)q;
      float res = f[j] - q * s;
      float lq = rintf(res * rs * 256.0f);
      lq = fminf(fmaxf(lq, -127.f), 127.f);
      L.c[j] = (signed char)(int)lq;
    }
    signed char* dst = c8 + (size_t)r * 512 + (d0 >> 6) * 128 + (d0 & 63);
    *(uint2*)dst        = H.u;
    *(uint2*)(dst + 64) = L.u;
    if ((t & 31) == 0) { sc[r] = s; csq[r] = ssq; }
  } else if (bid < 385) {
    const int i = (bid - 128) * 256 + t;
    ((float4*)dwzero)[i] = (float4){0.f, 0.f, 0.f, 0.f};
  } else {
    float s = ema_cs[t] + ema_cs[t + 256] + ema_cs[t + 512] + ema_cs[t + 768];
#pragma unroll
    for (int off = 32; off; off >>= 1) s += __shfl_down(s, off);
    __shared__ float wsum[4];
    if ((t & 63) == 0) wsum[t >> 6] = s;
    __syncthreads();
    if (t == 0) S[0] = wsum[0] + wsum[1] + wsum[2] + wsum[3];
  }
}

// ---------------------------------------------------------------- fused
// Block: 64 z-rows x K=1024. Waves 2x2: wr rows-half (32), wc cols-half (64).
// Unit u = (ct,kk): ct = col-tile of 128, kk = 64-elem K-chunk. 32 units/pass.
#define STAGE(u, buf) do {                                                   \
    const int ct_ = (u) >> 2, kk_ = (u) & 3;                                 \
    _Pragma("unroll")                                                        \
    for (int rnd = 0; rnd < 4; ++rnd) {                                      \
      const int cl_ = w * 32 + rnd * 8 + (lane >> 3);                        \
      const int p_  = lane & 7;                                              \
      gload16(c8 + (size_t)(ct_ * 128 + cl_) * 512 + kk_ * 128 +             \
                  ((p_ ^ (cl_ & 7)) * 16),                                   \
              &lB[buf][(w * 32 + rnd * 8) * 128]);                           \
    }                                                                        \
  } while (0)

__global__ __launch_bounds__(256, 2) void fused_vq(
    const float* __restrict__ z, const float* __restrict__ cent,
    const signed char* __restrict__ c8, const float* __restrict__ sc,
    const float* __restrict__ csq, float* __restrict__ gamma,
    float* __restrict__ recons, float* __restrict__ dw,
    float* __restrict__ counts) {
  __shared__ signed char lA[64 * 512];       // 32 KB, z-tile (h|l per kk, swizzled)
  __shared__ signed char lB[2][128 * 128];   // 32 KB, c8 dbuf
  __shared__ float sMv[16][64];
  __shared__ float sSv[16][64];
  __shared__ int   sIv[16][64];
  __shared__ float fM[64];
  __shared__ float fInv[64];
  __shared__ int   fIdx[64];
  __shared__ float sZs[64];

  const int t = threadIdx.x, lane = t & 63, w = t >> 6;
  const int hi = lane >> 5, l31 = lane & 31;
  const int wr = w >> 1, wc = w & 1;
  const int m0 = blockIdx.x * 64;

  // ---- quantize z rows m0..m0+63 into lA ----
  {
    const int c  = lane;
    const int kk = c >> 4, ch = (c & 15) >> 2, jb = (c & 3) * 4;
#pragma unroll 1
    for (int it = 0; it < 16; ++it) {
      const int r = it * 4 + w;
      const float4 v = *(const float4*)&z[(size_t)(m0 + r) * 256 + c * 4];
      float am = fmaxf(fmaxf(fabsf(v.x), fabsf(v.y)), fmaxf(fabsf(v.z), fabsf(v.w)));
#pragma unroll
      for (int off = 32; off; off >>= 1) am = fmaxf(am, __shfl_xor(am, off));
      const float s  = fmaxf(am, 1e-6f) * (1.0f / 127.0f);
      const float rs = 1.0f / s;
      const float f[4] = {v.x, v.y, v.z, v.w};
      unsigned int hw = 0, lw = 0;
#pragma unroll
      for (int j = 0; j < 4; ++j) {
        float q = rintf(f[j] * rs);
        q = fminf(fmaxf(q, -127.f), 127.f);
        float res = f[j] - q * s;
        float lq = rintf(res * rs * 256.0f);
        lq = fminf(fmaxf(lq, -127.f), 127.f);
        hw |= ((unsigned int)(unsigned char)(signed char)(int)q)  << (8 * j);
        lw |= ((unsigned int)(unsigned char)(signed char)(int)lq) << (8 * j);
      }
      const int haddr = r * 512 + kk * 128 + ((ch ^ (r & 7)) * 16) + jb;
      *(unsigned int*)&lA[haddr]      = hw;
      *(unsigned int*)&lA[haddr ^ 64] = lw;
      if (lane == 0) sZs[r] = s;
    }
  }
  __syncthreads();

  float szv[16];
#pragma unroll
  for (int reg = 0; reg < 16; ++reg)
    szv[reg] = sZs[wr * 32 + (reg & 3) + 8 * (reg >> 2) + 4 * hi];

  const int ra = wr * 32 + l31;

  i32x16 accA[2], accB[2];

#pragma unroll 1
  for (int pass = 0; pass < 2; ++pass) {
    STAGE(0, 0);
#pragma unroll 1
    for (int u = 0; u < 32; ++u) {
      const int cur = u & 1;
      const int ct = u >> 2, kk = u & 3;
      if (kk == 0) {
        accA[0] = (i32x16)(0); accA[1] = (i32x16)(0);
        accB[0] = (i32x16)(0); accB[1] = (i32x16)(0);
      }
      __syncthreads();
      if (u + 1 < 32) STAGE(u + 1, cur ^ 1);
#pragma unroll
      for (int s = 0; s < 2; ++s) {
        const int kc = s * 2 + hi;
        const i32x4 ah = *(const i32x4*)&lA[ra * 512 + kk * 128 + ((kc ^ (ra & 7)) * 16)];
        const i32x4 al = *(const i32x4*)&lA[ra * 512 + kk * 128 + (((kc + 4) ^ (ra & 7)) * 16)];
#pragma unroll
        for (int fj = 0; fj < 2; ++fj) {
          const int rb = wc * 64 + fj * 32 + l31;
          const i32x4 bh = *(const i32x4*)&lB[cur][rb * 128 + ((kc ^ (rb & 7)) * 16)];
          const i32x4 bl = *(const i32x4*)&lB[cur][rb * 128 + (((kc + 4) ^ (rb & 7)) * 16)];
          accA[fj] = __builtin_amdgcn_mfma_i32_32x32x32_i8(ah, bh, accA[fj], 0, 0, 0);
          accB[fj] = __builtin_amdgcn_mfma_i32_32x32x32_i8(ah, bl, accB[fj], 0, 0, 0);
          accB[fj] = __builtin_amdgcn_mfma_i32_32x32x32_i8(al, bh, accB[fj], 0, 0, 0);
        }
      }
      if (kk == 3) {
        const int cg0 = ct * 128 + wc * 64 + l31;
        const float sc0 = sc[cg0],      cq0 = csq[cg0];
        const float sc1 = sc[cg0 + 32], cq1 = csq[cg0 + 32];
        if (pass == 0) {
#pragma unroll
          for (int reg = 0; reg < 16; ++reg) {
            const float d0 = (float)accA[0][reg] + (float)accB[0][reg] * (1.0f / 256.0f);
            const float d1 = (float)accA[1][reg] + (float)accB[1][reg] * (1.0f / 256.0f);
            const float s0 = cq0 - 2.0f * szv[reg] * sc0 * d0;
            const float s1 = cq1 - 2.0f * szv[reg] * sc1 * d1;
            float mv; int mi;
            if (s1 < s0) { mv = s1; mi = cg0 + 32; } else { mv = s0; mi = cg0; }
#pragma unroll
            for (int off = 16; off; off >>= 1) {
              const float ov = __shfl_xor(mv, off);
              const int   oi = __shfl_xor(mi, off);
              if (ov < mv || (ov == mv && oi < mi)) { mv = ov; mi = oi; }
            }
            float e = __expf(-5.0f * (s0 - mv)) + __expf(-5.0f * (s1 - mv));
#pragma unroll
            for (int off = 16; off; off >>= 1) e += __shfl_xor(e, off);
            if (l31 == 0) {
              const int rl = wr * 32 + (reg & 3) + 8 * (reg >> 2) + 4 * hi;
              sMv[ct * 2 + wc][rl] = mv;
              sSv[ct * 2 + wc][rl] = e;
              sIv[ct * 2 + wc][rl] = mi;
            }
          }
        } else {
#pragma unroll
          for (int reg = 0; reg < 16; ++reg) {
            const int rl = wr * 32 + (reg & 3) + 8 * (reg >> 2) + 4 * hi;
            const float d0 = (float)accA[0][reg] + (float)accB[0][reg] * (1.0f / 256.0f);
            const float d1 = (float)accA[1][reg] + (float)accB[1][reg] * (1.0f / 256.0f);
            const float s0 = cq0 - 2.0f * szv[reg] * sc0 * d0;
            const float s1 = cq1 - 2.0f * szv[reg] * sc1 * d1;
            const float m = fM[rl], inv = fInv[rl];
            gamma[(size_t)(m0 + rl) * 1024 + cg0]      = __expf(-5.0f * (s0 - m)) * inv;
            gamma[(size_t)(m0 + rl) * 1024 + cg0 + 32] = __expf(-5.0f * (s1 - m)) * inv;
          }
        }
      }
    }
    if (pass == 0) {
      __syncthreads();
      if (t < 64) {
        float m = 3.0e38f; int mi = 0;
#pragma unroll
        for (int e = 0; e < 16; ++e) {
          const float me = sMv[e][t];
          if (me < m) { m = me; mi = sIv[e][t]; }
        }
        float sum = 0.f;
#pragma unroll
        for (int e = 0; e < 16; ++e)
          sum += sSv[e][t] * __expf(-5.0f * (sMv[e][t] - m));
        fM[t] = m; fInv[t] = 1.0f / sum; fIdx[t] = mi;
        atomicAdd(&counts[mi], 1.0f);
      }
      __syncthreads();
    }
  }

  // ---- epilogue: recons gather + dw scatter ----
#pragma unroll 1
  for (int it = 0; it < 16; ++it) {
    const int r = it * 4 + w;
    const int n = m0 + r;
    const int idx = fIdx[r];
    const float4 zv = *(const float4*)&z[(size_t)n * 256 + lane * 4];
    const float4 cv = *(const float4*)&cent[(size_t)idx * 256 + lane * 4];
    *(float4*)&recons[(size_t)n * 256 + lane * 4] = cv;
    float* dp = &dw[(size_t)idx * 256 + lane * 4];
    atomicAdd(dp + 0, zv.x);
    atomicAdd(dp + 1, zv.y);
    atomicAdd(dp + 2, zv.z);
    atomicAdd(dp + 3, zv.w);
  }
}

// ---------------------------------------------------------------- finalize
__global__ __launch_bounds__(256) void finalize(const float* __restrict__ ema_w,
                                                const float* __restrict__ ema_cs,
                                                const float* __restrict__ counts,
                                                const float* __restrict__ dw,
                                                const float* __restrict__ S,
                                                float* __restrict__ outc,
                                                float fN) {
  const int k = blockIdx.x;
  const int t = threadIdx.x;
  const float n   = DECAY * S[0] + OMD * fN;        // sum(new_cs): sum(counts)==N
  const float v   = DECAY * ema_cs[k] + OMD * counts[k];
  const float ncs = (v + EPSV) / (n + 1024.0f * EPSV) * n;
  const size_t i  = (size_t)k * 256 + t;
  outc[i] = (DECAY * ema_w[i] + OMD * dw[i]) / ncs;
}

// ---------------------------------------------------------------- launch
extern "C" void kernel_launch(void* const* d_in, const int* in_sizes, int n_in,
                              void* d_out, int out_size, void* d_ws, size_t ws_size,
                              hipStream_t stream) {
  const float* z      = (const float*)d_in[0];
  const float* cent   = (const float*)d_in[1];
  const float* ema_w  = (const float*)d_in[2];
  const float* ema_cs = (const float*)d_in[3];

  const int K = in_sizes[3];            // 1024
  const int D = in_sizes[1] / K;        // 256
  const int N = in_sizes[0] / D;        // 16384

  float* out    = (float*)d_out;
  float* recons = out;                              // [N,D]
  float* gamma  = out + (size_t)N * D;              // [N,K]
  float* outc   = gamma + (size_t)N * K;            // [K,D]

  // c8 + sc parked in outc region (read throughout fused; finalize writes last)
  signed char* c8 = (signed char*)outc;             // K*512 B = 512 KB
  float* sc = (float*)((char*)outc + (size_t)K * 512);  // K floats

  float* dw     = (float*)d_ws;                     // [K,D]
  float* counts = dw + (size_t)K * D;               // [K]
  float* csq    = counts + K;                       // [K]
  float* S      = csq + K;                          // [1]

  prep<<<386, 256, 0, stream>>>(cent, ema_cs, c8, sc, csq, dw, S);

  fused_vq<<<N / 64, 256, 0, stream>>>(z, cent, c8, sc, csq, gamma, recons, dw, counts);

  finalize<<<K, 256, 0, stream>>>(ema_w, ema_cs, counts, dw, S, outc, (float)N);
}

// Round 9
// 240.418 us; speedup vs baseline: 1.1864x; 1.1864x over previous
//
#include <hip/hip_runtime.h>

// VectorQuantizerEMA: N=16384, K=1024, D=256.
// Outputs (f32, concat): recons [N,D] | gamma [N,K] | new_centroids [K,D]
// R9: two-pass recompute fusion. gemmA: i8 MFMA dist tiles -> per-(row,64col)
// stats only (no dist write). merge: per-row m/inv/idx + counts. gemmB:
// recompute (bit-identical int accs) -> write normalized gamma directly.
// dist never touches memory. epi: recons gather + dw scatter. 6 kernels.

#define DECAY 0.95f
#define OMD   0.05f
#define EPSV  1e-5f

using i32x4  = __attribute__((ext_vector_type(4))) int;
using i32x16 = __attribute__((ext_vector_type(16))) int;

typedef __attribute__((address_space(3))) unsigned int       lds_uint;
typedef const __attribute__((address_space(1))) unsigned int glb_uint;

__device__ __forceinline__ void gload16(const void* g, const void* l) {
  __builtin_amdgcn_global_load_lds((glb_uint*)(unsigned long long)g,
                                   (lds_uint*)(unsigned int)(unsigned long long)l,
                                   16, 0, 0);
}

// ---------------------------------------------------------------- prep (as R7)
// bid 0..2047    : z int8 hi/lo quantize (8 rows/block) + sz
// bid 2048..2175 : cent int8 quantize + sc + csq
// bid 2176..2432 : zero dw+counts
// bid 2433       : S = sum(ema_cs)
__global__ __launch_bounds__(256) void prep(const float* __restrict__ z,
                                            const float* __restrict__ cent,
                                            const float* __restrict__ ema_cs,
                                            signed char* __restrict__ z8,
                                            signed char* __restrict__ c8,
                                            float* __restrict__ sz,
                                            float* __restrict__ sc,
                                            float* __restrict__ csq,
                                            float* __restrict__ dwzero,
                                            float* __restrict__ S) {
  const int bid = blockIdx.x;
  const int t   = threadIdx.x;
  if (bid < 2176) {
    const bool isz = bid < 2048;
    const float* src = isz ? z : cent;
    const int rb = isz ? bid : (bid - 2048);
    const int r  = rb * 8 + (t >> 5);
    const int d0 = (t & 31) * 8;
    const float4 a = *(const float4*)&src[(size_t)r * 256 + d0];
    const float4 b = *(const float4*)&src[(size_t)r * 256 + d0 + 4];
    float f[8] = {a.x, a.y, a.z, a.w, b.x, b.y, b.z, b.w};
    float am = 0.f, ssq = 0.f;
#pragma unroll
    for (int j = 0; j < 8; ++j) { am = fmaxf(am, fabsf(f[j])); ssq += f[j] * f[j]; }
#pragma unroll
    for (int off = 16; off; off >>= 1) {
      am  = fmaxf(am, __shfl_down(am, off, 32));
      ssq += __shfl_down(ssq, off, 32);
    }
    am = __shfl(am, 0, 32);
    const float s  = fmaxf(am, 1e-6f) * (1.0f / 127.0f);
    const float rs = 1.0f / s;
    union { signed char c[8]; uint2 u; } H, L;
#pragma unroll
    for (int j = 0; j < 8; ++j) {
      float q = rintf(f[j] * rs);
      q = fminf(fmaxf(q, -127.f), 127.f);
      H.c[j] = (signed char)(int)q;
      float res = f[j] - q * s;
      float lq = rintf(res * rs * 256.0f);
      lq = fminf(fmaxf(lq, -127.f), 127.f);
      L.c[j] = (signed char)(int)lq;
    }
    signed char* dst = (isz ? z8 : c8) + (size_t)r * 512 + (d0 >> 6) * 128 + (d0 & 63);
    *(uint2*)dst        = H.u;
    *(uint2*)(dst + 64) = L.u;
    if ((t & 31) == 0) {
      if (isz) sz[r] = s;
      else { sc[r] = s; csq[r] = ssq; }
    }
  } else if (bid < 2433) {
    const int i = (bid - 2176) * 256 + t;
    ((float4*)dwzero)[i] = (float4){0.f, 0.f, 0.f, 0.f};
  } else {
    float s = ema_cs[t] + ema_cs[t + 256] + ema_cs[t + 512] + ema_cs[t + 768];
#pragma unroll
    for (int off = 32; off; off >>= 1) s += __shfl_down(s, off);
    __shared__ float wsum[4];
    if ((t & 63) == 0) wsum[t >> 6] = s;
    __syncthreads();
    if (t == 0) S[0] = wsum[0] + wsum[1] + wsum[2] + wsum[3];
  }
}

// ---------------------------------------------------------------- i8 GEMM core
// PASS 0: write per-(row, 64-col-block) stats {min, expsum, argmin}.
// PASS 1: recompute + write normalized gamma using fM/fInv.
template <int PASS>
__global__ __launch_bounds__(256, 2) void dist_gemm_i8(
    const signed char* __restrict__ z8, const signed char* __restrict__ c8,
    const float* __restrict__ sz, const float* __restrict__ sc,
    const float* __restrict__ csq,
    float* __restrict__ sm, float* __restrict__ se, int* __restrict__ si,
    const float* __restrict__ fM, const float* __restrict__ fInv,
    float* __restrict__ gamma) {
  __shared__ signed char lds[2][128 * 128];   // 32 KB
  __shared__ float fMl[128], fIl[128];

  const int tid  = threadIdx.x;
  const int lane = tid & 63;
  const int w    = tid >> 6;
  const int hi   = lane >> 5, l31 = lane & 31;

  const int bid = blockIdx.x;
  const int lin = (bid & 7) * 128 + (bid >> 3);   // XCD-bijective (1024 % 8 == 0)
  const int m0  = (lin >> 3) * 128;
  const int n0  = (lin & 7) * 128;

  const int wm0 = (w >> 1) * 64;
  const int wn0 = (w & 1) * 64;
  const int wc  = w & 1;

  if (PASS == 1 && tid < 128) { fMl[tid] = fM[m0 + tid]; fIl[tid] = fInv[m0 + tid]; }

  i32x16 accA[2][2], accB[2][2];
#pragma unroll
  for (int i = 0; i < 2; ++i)
#pragma unroll
    for (int j = 0; j < 2; ++j) { accA[i][j] = (i32x16)(0); accB[i][j] = (i32x16)(0); }

  const int srow = lane >> 3;
  const int scb  = lane & 7;

  for (int kk = 0; kk < 4; ++kk) {
    __syncthreads();
#pragma unroll
    for (int j = 0; j < 4; ++j) {
      const int r0    = w * 32 + j * 8;
      const int row   = r0 + srow;
      const int chunk = scb ^ (row & 7);
      gload16(z8 + (size_t)(m0 + row) * 512 + kk * 128 + chunk * 16, &lds[0][r0 * 128]);
      gload16(c8 + (size_t)(n0 + row) * 512 + kk * 128 + chunk * 16, &lds[1][r0 * 128]);
    }
    __syncthreads();
#pragma unroll
    for (int s = 0; s < 2; ++s) {
      i32x4 ah[2], al[2], bh[2], bl[2];
      const int kc = s * 2 + hi;
#pragma unroll
      for (int fi = 0; fi < 2; ++fi) {
        const int ra = wm0 + fi * 32 + l31;
        ah[fi] = *(const i32x4*)&lds[0][ra * 128 + ((kc)     ^ (ra & 7)) * 16];
        al[fi] = *(const i32x4*)&lds[0][ra * 128 + ((kc + 4) ^ (ra & 7)) * 16];
        const int rb = wn0 + fi * 32 + l31;
        bh[fi] = *(const i32x4*)&lds[1][rb * 128 + ((kc)     ^ (rb & 7)) * 16];
        bl[fi] = *(const i32x4*)&lds[1][rb * 128 + ((kc + 4) ^ (rb & 7)) * 16];
      }
#pragma unroll
      for (int i = 0; i < 2; ++i)
#pragma unroll
        for (int j = 0; j < 2; ++j) {
          accA[i][j] = __builtin_amdgcn_mfma_i32_32x32x32_i8(ah[i], bh[j], accA[i][j], 0, 0, 0);
          accB[i][j] = __builtin_amdgcn_mfma_i32_32x32x32_i8(ah[i], bl[j], accB[i][j], 0, 0, 0);
          accB[i][j] = __builtin_amdgcn_mfma_i32_32x32x32_i8(al[i], bh[j], accB[i][j], 0, 0, 0);
        }
    }
  }

  const int colb = n0 + wn0 + l31;          // j=0 col; j=1 is colb+32
  const float sc0 = sc[colb],      cq0 = csq[colb];
  const float sc1 = sc[colb + 32], cq1 = csq[colb + 32];
  const int cb16 = (lin & 7) * 2 + wc;      // 64-col block index 0..15

#pragma unroll
  for (int i = 0; i < 2; ++i) {
#pragma unroll
    for (int reg = 0; reg < 16; ++reg) {
      const int lr = wm0 + i * 32 + (reg & 3) + 8 * (reg >> 2) + 4 * hi;
      const float szr = sz[m0 + lr];
      const float d0 = (float)accA[i][0][reg] + (float)accB[i][0][reg] * (1.0f / 256.0f);
      const float d1 = (float)accA[i][1][reg] + (float)accB[i][1][reg] * (1.0f / 256.0f);
      const float s0 = cq0 - 2.0f * szr * sc0 * d0;
      const float s1 = cq1 - 2.0f * szr * sc1 * d1;
      if (PASS == 0) {
        float mv; int mi;
        if (s1 < s0) { mv = s1; mi = colb + 32; } else { mv = s0; mi = colb; }
#pragma unroll
        for (int off = 16; off; off >>= 1) {
          const float ov = __shfl_xor(mv, off);
          const int   oi = __shfl_xor(mi, off);
          if (ov < mv || (ov == mv && oi < mi)) { mv = ov; mi = oi; }
        }
        float e = __expf(-5.0f * (s0 - mv)) + __expf(-5.0f * (s1 - mv));
#pragma unroll
        for (int off = 16; off; off >>= 1) e += __shfl_xor(e, off);
        if (l31 == 0) {
          const int gr = cb16 * 16384 + m0 + lr;
          sm[gr] = mv; se[gr] = e; si[gr] = mi;
        }
      } else {
        const float m = fMl[lr], inv = fIl[lr];
        float* gp = &gamma[(size_t)(m0 + lr) * 1024];
        gp[colb]      = __expf(-5.0f * (s0 - m)) * inv;
        gp[colb + 32] = __expf(-5.0f * (s1 - m)) * inv;
      }
    }
  }
}

// ---------------------------------------------------------------- merge
__global__ __launch_bounds__(256) void merge_stats(const float* __restrict__ sm,
                                                   const float* __restrict__ se,
                                                   const int* __restrict__ si,
                                                   float* __restrict__ fM,
                                                   float* __restrict__ fInv,
                                                   int* __restrict__ fIdx,
                                                   float* __restrict__ counts) {
  const int r = blockIdx.x * 256 + threadIdx.x;
  float m = sm[r]; int mi = si[r];
#pragma unroll
  for (int cb = 1; cb < 16; ++cb) {
    const float mt = sm[cb * 16384 + r];
    const int   it = si[cb * 16384 + r];
    if (mt < m || (mt == m && it < mi)) { m = mt; mi = it; }
  }
  float sum = 0.f;
#pragma unroll
  for (int cb = 0; cb < 16; ++cb)
    sum += se[cb * 16384 + r] * __expf(-5.0f * (sm[cb * 16384 + r] - m));
  fM[r] = m; fInv[r] = 1.0f / sum; fIdx[r] = mi;
  atomicAdd(&counts[mi], 1.0f);
}

// ---------------------------------------------------------------- epi: recons + dw
__global__ __launch_bounds__(256) void epi(const float* __restrict__ z,
                                           const float* __restrict__ cent,
                                           const int* __restrict__ fIdx,
                                           float* __restrict__ recons,
                                           float* __restrict__ dw) {
  const int r    = blockIdx.x * 4 + (threadIdx.x >> 6);
  const int lane = threadIdx.x & 63;
  const int idx  = fIdx[r];
  const float4 zv = *(const float4*)&z[(size_t)r * 256 + lane * 4];
  const float4 cv = *(const float4*)&cent[(size_t)idx * 256 + lane * 4];
  *(float4*)&recons[(size_t)r * 256 + lane * 4] = cv;
  float* dp = &dw[(size_t)idx * 256 + lane * 4];
  atomicAdd(dp + 0, zv.x);
  atomicAdd(dp + 1, zv.y);
  atomicAdd(dp + 2, zv.z);
  atomicAdd(dp + 3, zv.w);
}

// ---------------------------------------------------------------- finalize
__global__ __launch_bounds__(256) void finalize(const float* __restrict__ ema_w,
                                                const float* __restrict__ ema_cs,
                                                const float* __restrict__ counts,
                                                const float* __restrict__ dw,
                                                const float* __restrict__ S,
                                                float* __restrict__ outc,
                                                float fN) {
  const int k = blockIdx.x;
  const int t = threadIdx.x;
  const float n   = DECAY * S[0] + OMD * fN;
  const float v   = DECAY * ema_cs[k] + OMD * counts[k];
  const float ncs = (v + EPSV) / (n + 1024.0f * EPSV) * n;
  const size_t i  = (size_t)k * 256 + t;
  outc[i] = (DECAY * ema_w[i] + OMD * dw[i]) / ncs;
}

// ---------------------------------------------------------------- launch
extern "C" void kernel_launch(void* const* d_in, const int* in_sizes, int n_in,
                              void* d_out, int out_size, void* d_ws, size_t ws_size,
                              hipStream_t stream) {
  const float* z      = (const float*)d_in[0];
  const float* cent   = (const float*)d_in[1];
  const float* ema_w  = (const float*)d_in[2];
  const float* ema_cs = (const float*)d_in[3];

  const int K = in_sizes[3];            // 1024
  const int D = in_sizes[1] / K;        // 256
  const int N = in_sizes[0] / D;        // 16384

  float* out    = (float*)d_out;
  float* recons = out;                              // [N,D] = 16 MB
  float* gamma  = out + (size_t)N * D;              // [N,K]
  float* outc   = gamma + (size_t)N * K;            // [K,D] = 1 MB

  // recons region scratch (dead before epi writes recons):
  signed char* z8 = (signed char*)recons;           // 8 MB
  float* sm = (float*)((char*)recons + (size_t)8 * 1024 * 1024);  // 16x16384 f32
  float* se = sm + 16 * 16384;                      // 1 MB
  int*   si = (int*)(se + 16 * 16384);              // 1 MB  (total 11 MB < 16 MB)

  // outc region scratch (finalize writes outc last):
  signed char* c8 = (signed char*)outc;             // 512 KB
  float* sz = (float*)((char*)outc + (size_t)K * 512);  // N floats
  float* sc = sz + N;                               // K floats

  float* dw     = (float*)d_ws;                     // [K,D] 1 MB
  float* counts = dw + (size_t)K * D;               // [K]
  float* csq    = counts + K;                       // [K]
  float* S      = csq + K;                          // [1]
  float* fM     = S + 1;                            // [N]
  float* fInv   = fM + N;                           // [N]
  int*   fIdx   = (int*)(fInv + N);                 // [N]  (ws total ~1.24 MB)

  prep<<<2434, 256, 0, stream>>>(z, cent, ema_cs, z8, c8, sz, sc, csq, dw, S);

  dist_gemm_i8<0><<<(N / 128) * (K / 128), 256, 0, stream>>>(
      z8, c8, sz, sc, csq, sm, se, si, fM, fInv, gamma);

  merge_stats<<<N / 256, 256, 0, stream>>>(sm, se, si, fM, fInv, fIdx, counts);

  dist_gemm_i8<1><<<(N / 128) * (K / 128), 256, 0, stream>>>(
      z8, c8, sz, sc, csq, sm, se, si, fM, fInv, gamma);

  epi<<<N / 4, 256, 0, stream>>>(z, cent, fIdx, recons, dw);

  finalize<<<K, 256, 0, stream>>>(ema_w, ema_cs, counts, dw, S, outc, (float)N);
}

// Round 10
// 168.580 us; speedup vs baseline: 1.6920x; 1.4261x over previous
//
#include <hip/hip_runtime.h>

// VectorQuantizerEMA: N=16384, K=1024, D=256.
// Outputs (f32, concat): recons [N,D] | gamma [N,K] | new_centroids [K,D]
// R10: R9's two-pass recompute fusion, with the float-atomic epilogue replaced
// by a deterministic per-centroid segment-sum (dwfin): ballot-scan of fIdx,
// coalesced z accumulate, recons write, inline EMA finalize. No float atomics.

#define DECAY 0.95f
#define OMD   0.05f
#define EPSV  1e-5f

using i32x4  = __attribute__((ext_vector_type(4))) int;
using i32x16 = __attribute__((ext_vector_type(16))) int;

typedef __attribute__((address_space(3))) unsigned int       lds_uint;
typedef const __attribute__((address_space(1))) unsigned int glb_uint;

__device__ __forceinline__ void gload16(const void* g, const void* l) {
  __builtin_amdgcn_global_load_lds((glb_uint*)(unsigned long long)g,
                                   (lds_uint*)(unsigned int)(unsigned long long)l,
                                   16, 0, 0);
}

// ---------------------------------------------------------------- prep
// bid 0..2047    : z int8 hi/lo quantize (8 rows/block) + sz
// bid 2048..2175 : cent int8 quantize + sc + csq
// bid 2176       : S = sum(ema_cs)
__global__ __launch_bounds__(256) void prep(const float* __restrict__ z,
                                            const float* __restrict__ cent,
                                            const float* __restrict__ ema_cs,
                                            signed char* __restrict__ z8,
                                            signed char* __restrict__ c8,
                                            float* __restrict__ sz,
                                            float* __restrict__ sc,
                                            float* __restrict__ csq,
                                            float* __restrict__ S) {
  const int bid = blockIdx.x;
  const int t   = threadIdx.x;
  if (bid < 2176) {
    const bool isz = bid < 2048;
    const float* src = isz ? z : cent;
    const int rb = isz ? bid : (bid - 2048);
    const int r  = rb * 8 + (t >> 5);
    const int d0 = (t & 31) * 8;
    const float4 a = *(const float4*)&src[(size_t)r * 256 + d0];
    const float4 b = *(const float4*)&src[(size_t)r * 256 + d0 + 4];
    float f[8] = {a.x, a.y, a.z, a.w, b.x, b.y, b.z, b.w};
    float am = 0.f, ssq = 0.f;
#pragma unroll
    for (int j = 0; j < 8; ++j) { am = fmaxf(am, fabsf(f[j])); ssq += f[j] * f[j]; }
#pragma unroll
    for (int off = 16; off; off >>= 1) {
      am  = fmaxf(am, __shfl_down(am, off, 32));
      ssq += __shfl_down(ssq, off, 32);
    }
    am = __shfl(am, 0, 32);
    const float s  = fmaxf(am, 1e-6f) * (1.0f / 127.0f);
    const float rs = 1.0f / s;
    union { signed char c[8]; uint2 u; } H, L;
#pragma unroll
    for (int j = 0; j < 8; ++j) {
      float q = rintf(f[j] * rs);
      q = fminf(fmaxf(q, -127.f), 127.f);
      H.c[j] = (signed char)(int)q;
      float res = f[j] - q * s;
      float lq = rintf(res * rs * 256.0f);
      lq = fminf(fmaxf(lq, -127.f), 127.f);
      L.c[j] = (signed char)(int)lq;
    }
    signed char* dst = (isz ? z8 : c8) + (size_t)r * 512 + (d0 >> 6) * 128 + (d0 & 63);
    *(uint2*)dst        = H.u;
    *(uint2*)(dst + 64) = L.u;
    if ((t & 31) == 0) {
      if (isz) sz[r] = s;
      else { sc[r] = s; csq[r] = ssq; }
    }
  } else {
    float s = ema_cs[t] + ema_cs[t + 256] + ema_cs[t + 512] + ema_cs[t + 768];
#pragma unroll
    for (int off = 32; off; off >>= 1) s += __shfl_down(s, off);
    __shared__ float wsum[4];
    if ((t & 63) == 0) wsum[t >> 6] = s;
    __syncthreads();
    if (t == 0) S[0] = wsum[0] + wsum[1] + wsum[2] + wsum[3];
  }
}

// ---------------------------------------------------------------- i8 GEMM core
// PASS 0: write per-(row, 64-col-block) stats {min, expsum, argmin}.
// PASS 1: recompute + write normalized gamma using fM/fInv.
template <int PASS>
__global__ __launch_bounds__(256, 2) void dist_gemm_i8(
    const signed char* __restrict__ z8, const signed char* __restrict__ c8,
    const float* __restrict__ sz, const float* __restrict__ sc,
    const float* __restrict__ csq,
    float* __restrict__ sm, float* __restrict__ se, int* __restrict__ si,
    const float* __restrict__ fM, const float* __restrict__ fInv,
    float* __restrict__ gamma) {
  __shared__ signed char lds[2][128 * 128];   // 32 KB
  __shared__ float fMl[128], fIl[128];

  const int tid  = threadIdx.x;
  const int lane = tid & 63;
  const int w    = tid >> 6;
  const int hi   = lane >> 5, l31 = lane & 31;

  const int bid = blockIdx.x;
  const int lin = (bid & 7) * 128 + (bid >> 3);   // XCD-bijective (1024 % 8 == 0)
  const int m0  = (lin >> 3) * 128;
  const int n0  = (lin & 7) * 128;

  const int wm0 = (w >> 1) * 64;
  const int wn0 = (w & 1) * 64;
  const int wc  = w & 1;

  if (PASS == 1 && tid < 128) { fMl[tid] = fM[m0 + tid]; fIl[tid] = fInv[m0 + tid]; }

  i32x16 accA[2][2], accB[2][2];
#pragma unroll
  for (int i = 0; i < 2; ++i)
#pragma unroll
    for (int j = 0; j < 2; ++j) { accA[i][j] = (i32x16)(0); accB[i][j] = (i32x16)(0); }

  const int srow = lane >> 3;
  const int scb  = lane & 7;

  for (int kk = 0; kk < 4; ++kk) {
    __syncthreads();
#pragma unroll
    for (int j = 0; j < 4; ++j) {
      const int r0    = w * 32 + j * 8;
      const int row   = r0 + srow;
      const int chunk = scb ^ (row & 7);
      gload16(z8 + (size_t)(m0 + row) * 512 + kk * 128 + chunk * 16, &lds[0][r0 * 128]);
      gload16(c8 + (size_t)(n0 + row) * 512 + kk * 128 + chunk * 16, &lds[1][r0 * 128]);
    }
    __syncthreads();
#pragma unroll
    for (int s = 0; s < 2; ++s) {
      i32x4 ah[2], al[2], bh[2], bl[2];
      const int kc = s * 2 + hi;
#pragma unroll
      for (int fi = 0; fi < 2; ++fi) {
        const int ra = wm0 + fi * 32 + l31;
        ah[fi] = *(const i32x4*)&lds[0][ra * 128 + ((kc)     ^ (ra & 7)) * 16];
        al[fi] = *(const i32x4*)&lds[0][ra * 128 + ((kc + 4) ^ (ra & 7)) * 16];
        const int rb = wn0 + fi * 32 + l31;
        bh[fi] = *(const i32x4*)&lds[1][rb * 128 + ((kc)     ^ (rb & 7)) * 16];
        bl[fi] = *(const i32x4*)&lds[1][rb * 128 + ((kc + 4) ^ (rb & 7)) * 16];
      }
#pragma unroll
      for (int i = 0; i < 2; ++i)
#pragma unroll
        for (int j = 0; j < 2; ++j) {
          accA[i][j] = __builtin_amdgcn_mfma_i32_32x32x32_i8(ah[i], bh[j], accA[i][j], 0, 0, 0);
          accB[i][j] = __builtin_amdgcn_mfma_i32_32x32x32_i8(ah[i], bl[j], accB[i][j], 0, 0, 0);
          accB[i][j] = __builtin_amdgcn_mfma_i32_32x32x32_i8(al[i], bh[j], accB[i][j], 0, 0, 0);
        }
    }
  }

  const int colb = n0 + wn0 + l31;          // j=0 col; j=1 is colb+32
  const float sc0 = sc[colb],      cq0 = csq[colb];
  const float sc1 = sc[colb + 32], cq1 = csq[colb + 32];
  const int cb16 = (lin & 7) * 2 + wc;      // 64-col block index 0..15

#pragma unroll
  for (int i = 0; i < 2; ++i) {
#pragma unroll
    for (int reg = 0; reg < 16; ++reg) {
      const int lr = wm0 + i * 32 + (reg & 3) + 8 * (reg >> 2) + 4 * hi;
      const float szr = sz[m0 + lr];
      const float d0 = (float)accA[i][0][reg] + (float)accB[i][0][reg] * (1.0f / 256.0f);
      const float d1 = (float)accA[i][1][reg] + (float)accB[i][1][reg] * (1.0f / 256.0f);
      const float s0 = cq0 - 2.0f * szr * sc0 * d0;
      const float s1 = cq1 - 2.0f * szr * sc1 * d1;
      if (PASS == 0) {
        float mv; int mi;
        if (s1 < s0) { mv = s1; mi = colb + 32; } else { mv = s0; mi = colb; }
#pragma unroll
        for (int off = 16; off; off >>= 1) {
          const float ov = __shfl_xor(mv, off);
          const int   oi = __shfl_xor(mi, off);
          if (ov < mv || (ov == mv && oi < mi)) { mv = ov; mi = oi; }
        }
        float e = __expf(-5.0f * (s0 - mv)) + __expf(-5.0f * (s1 - mv));
#pragma unroll
        for (int off = 16; off; off >>= 1) e += __shfl_xor(e, off);
        if (l31 == 0) {
          const int gr = cb16 * 16384 + m0 + lr;
          sm[gr] = mv; se[gr] = e; si[gr] = mi;
        }
      } else {
        const float m = fMl[lr], inv = fIl[lr];
        float* gp = &gamma[(size_t)(m0 + lr) * 1024];
        gp[colb]      = __expf(-5.0f * (s0 - m)) * inv;
        gp[colb + 32] = __expf(-5.0f * (s1 - m)) * inv;
      }
    }
  }
}

// ---------------------------------------------------------------- merge (no atomics)
__global__ __launch_bounds__(256) void merge_stats(const float* __restrict__ sm,
                                                   const float* __restrict__ se,
                                                   const int* __restrict__ si,
                                                   float* __restrict__ fM,
                                                   float* __restrict__ fInv,
                                                   int* __restrict__ fIdx) {
  const int r = blockIdx.x * 256 + threadIdx.x;
  float m = sm[r]; int mi = si[r];
#pragma unroll
  for (int cb = 1; cb < 16; ++cb) {
    const float mt = sm[cb * 16384 + r];
    const int   it = si[cb * 16384 + r];
    if (mt < m || (mt == m && it < mi)) { m = mt; mi = it; }
  }
  float sum = 0.f;
#pragma unroll
  for (int cb = 0; cb < 16; ++cb)
    sum += se[cb * 16384 + r] * __expf(-5.0f * (sm[cb * 16384 + r] - m));
  fM[r] = m; fInv[r] = 1.0f / sum; fIdx[r] = mi;
}

// ---------------------------------------------------------------- dwfin
// Block k: ballot-scan fIdx; for matching rows write recons[r]=cent[k] and
// accumulate z[r]; then outc[k] = (DECAY*ema_w[k] + OMD*dw) / newcs.
// Summation ascending in r per wave, waves reduced pairwise (matches
// segment_sum to fp-assoc noise). No atomics anywhere.
__global__ __launch_bounds__(256) void dwfin(const float* __restrict__ z,
                                             const float* __restrict__ cent,
                                             const float* __restrict__ ema_w,
                                             const float* __restrict__ ema_cs,
                                             const int* __restrict__ fIdx,
                                             const float* __restrict__ S,
                                             float* __restrict__ recons,
                                             float* __restrict__ outc,
                                             float fN, int N) {
  __shared__ float part[4][256];
  __shared__ int scnt[4];
  const int k    = blockIdx.x;
  const int w    = threadIdx.x >> 6;
  const int lane = threadIdx.x & 63;
  const int Q    = N >> 2;                         // rows per wave

  const float4 cv = *(const float4*)&cent[(size_t)k * 256 + lane * 4];

  float4 acc = {0.f, 0.f, 0.f, 0.f};
  int cnt = 0;
  const int base = w * Q;
  for (int c = 0; c < Q; c += 64) {
    const int fi = fIdx[base + c + lane];
    unsigned long long mask = __ballot(fi == k);
    cnt += __popcll(mask);
    while (mask) {
      const int b = __builtin_ctzll(mask);
      mask &= mask - 1;
      const int rr = base + c + b;
      const float4 zv = *(const float4*)&z[(size_t)rr * 256 + lane * 4];
      acc.x += zv.x; acc.y += zv.y; acc.z += zv.z; acc.w += zv.w;
      *(float4*)&recons[(size_t)rr * 256 + lane * 4] = cv;
    }
  }
  *(float4*)&part[w][lane * 4] = acc;
  if (lane == 0) scnt[w] = cnt;
  __syncthreads();
  if (w == 0) {
    const float4 a0 = *(const float4*)&part[0][lane * 4];
    const float4 a1 = *(const float4*)&part[1][lane * 4];
    const float4 a2 = *(const float4*)&part[2][lane * 4];
    const float4 a3 = *(const float4*)&part[3][lane * 4];
    float4 tot;
    tot.x = (a0.x + a1.x) + (a2.x + a3.x);
    tot.y = (a0.y + a1.y) + (a2.y + a3.y);
    tot.z = (a0.z + a1.z) + (a2.z + a3.z);
    tot.w = (a0.w + a1.w) + (a2.w + a3.w);
    const int  c   = (scnt[0] + scnt[1]) + (scnt[2] + scnt[3]);
    const float n  = DECAY * S[0] + OMD * fN;      // sum(new_cs): sum(counts)==N
    const float v  = DECAY * ema_cs[k] + OMD * (float)c;
    const float ncs = (v + EPSV) / (n + 1024.0f * EPSV) * n;
    const float rinv = 1.0f / ncs;
    const float4 w4 = *(const float4*)&ema_w[(size_t)k * 256 + lane * 4];
    float4 o;
    o.x = (DECAY * w4.x + OMD * tot.x) * rinv;
    o.y = (DECAY * w4.y + OMD * tot.y) * rinv;
    o.z = (DECAY * w4.z + OMD * tot.z) * rinv;
    o.w = (DECAY * w4.w + OMD * tot.w) * rinv;
    *(float4*)&outc[(size_t)k * 256 + lane * 4] = o;
  }
}

// ---------------------------------------------------------------- launch
extern "C" void kernel_launch(void* const* d_in, const int* in_sizes, int n_in,
                              void* d_out, int out_size, void* d_ws, size_t ws_size,
                              hipStream_t stream) {
  const float* z      = (const float*)d_in[0];
  const float* cent   = (const float*)d_in[1];
  const float* ema_w  = (const float*)d_in[2];
  const float* ema_cs = (const float*)d_in[3];

  const int K = in_sizes[3];            // 1024
  const int D = in_sizes[1] / K;        // 256
  const int N = in_sizes[0] / D;        // 16384

  float* out    = (float*)d_out;
  float* recons = out;                              // [N,D] = 16 MB
  float* gamma  = out + (size_t)N * D;              // [N,K]
  float* outc   = gamma + (size_t)N * K;            // [K,D] = 1 MB

  // recons region scratch (dead before dwfin writes recons):
  signed char* z8 = (signed char*)recons;           // 8 MB
  float* sm = (float*)((char*)recons + (size_t)8 * 1024 * 1024);  // 16x16384 f32
  float* se = sm + 16 * 16384;                      // 1 MB
  int*   si = (int*)(se + 16 * 16384);              // 1 MB  (total 11 MB < 16 MB)

  // outc region scratch (dwfin writes outc last, after gemmB reads c8):
  signed char* c8 = (signed char*)outc;             // 512 KB
  float* sz = (float*)((char*)outc + (size_t)K * 512);  // N floats
  float* sc = sz + N;                               // K floats

  float* csq  = (float*)d_ws;                       // [K]
  float* S    = csq + K;                            // [1]
  float* fM   = S + 1;                              // [N]
  float* fInv = fM + N;                             // [N]
  int*   fIdx = (int*)(fInv + N);                   // [N]  (ws ~200 KB)

  prep<<<2177, 256, 0, stream>>>(z, cent, ema_cs, z8, c8, sz, sc, csq, S);

  dist_gemm_i8<0><<<(N / 128) * (K / 128), 256, 0, stream>>>(
      z8, c8, sz, sc, csq, sm, se, si, fM, fInv, gamma);

  merge_stats<<<N / 256, 256, 0, stream>>>(sm, se, si, fM, fInv, fIdx);

  dist_gemm_i8<1><<<(N / 128) * (K / 128), 256, 0, stream>>>(
      z8, c8, sz, sc, csq, sm, se, si, fM, fInv, gamma);

  dwfin<<<K, 256, 0, stream>>>(z, cent, ema_w, ema_cs, fIdx, S, recons, outc,
                               (float)N, N);
}

// Round 11
// 123.499 us; speedup vs baseline: 2.3096x; 1.3650x over previous
//
#include <hip/hip_runtime.h>

// VectorQuantizerEMA: N=16384, K=1024, D=256.
// Outputs (f32, concat): recons [N,D] | gamma [N,K] | new_centroids [K,D]
// R11: composition of verified-fast pieces only.
//   prep: i8 hi/lo quantize z+cent, csq, S=sum(ema_cs). (R10, verified)
//   dist_gemm_i8: single-pass 128x128 MFMA tile -> dist. (R7 verbatim, fast)
//   row_softmax: block-per-row, gamma in-place + fIdx only — NO atomics.
//   dwfin: per-centroid ballot segment-sum + recons + inline EMA. (R10, fast)

#define DECAY 0.95f
#define OMD   0.05f
#define EPSV  1e-5f

using i32x4  = __attribute__((ext_vector_type(4))) int;
using i32x16 = __attribute__((ext_vector_type(16))) int;

typedef __attribute__((address_space(3))) unsigned int       lds_uint;
typedef const __attribute__((address_space(1))) unsigned int glb_uint;

__device__ __forceinline__ void gload16(const void* g, const void* l) {
  __builtin_amdgcn_global_load_lds((glb_uint*)(unsigned long long)g,
                                   (lds_uint*)(unsigned int)(unsigned long long)l,
                                   16, 0, 0);
}

// ---------------------------------------------------------------- prep
// bid 0..2047    : z int8 hi/lo quantize (8 rows/block) + sz
// bid 2048..2175 : cent int8 quantize + sc + csq
// bid 2176       : S = sum(ema_cs)
__global__ __launch_bounds__(256) void prep(const float* __restrict__ z,
                                            const float* __restrict__ cent,
                                            const float* __restrict__ ema_cs,
                                            signed char* __restrict__ z8,
                                            signed char* __restrict__ c8,
                                            float* __restrict__ sz,
                                            float* __restrict__ sc,
                                            float* __restrict__ csq,
                                            float* __restrict__ S) {
  const int bid = blockIdx.x;
  const int t   = threadIdx.x;
  if (bid < 2176) {
    const bool isz = bid < 2048;
    const float* src = isz ? z : cent;
    const int rb = isz ? bid : (bid - 2048);
    const int r  = rb * 8 + (t >> 5);
    const int d0 = (t & 31) * 8;
    const float4 a = *(const float4*)&src[(size_t)r * 256 + d0];
    const float4 b = *(const float4*)&src[(size_t)r * 256 + d0 + 4];
    float f[8] = {a.x, a.y, a.z, a.w, b.x, b.y, b.z, b.w};
    float am = 0.f, ssq = 0.f;
#pragma unroll
    for (int j = 0; j < 8; ++j) { am = fmaxf(am, fabsf(f[j])); ssq += f[j] * f[j]; }
#pragma unroll
    for (int off = 16; off; off >>= 1) {
      am  = fmaxf(am, __shfl_down(am, off, 32));
      ssq += __shfl_down(ssq, off, 32);
    }
    am = __shfl(am, 0, 32);
    const float s  = fmaxf(am, 1e-6f) * (1.0f / 127.0f);
    const float rs = 1.0f / s;
    union { signed char c[8]; uint2 u; } H, L;
#pragma unroll
    for (int j = 0; j < 8; ++j) {
      float q = rintf(f[j] * rs);
      q = fminf(fmaxf(q, -127.f), 127.f);
      H.c[j] = (signed char)(int)q;
      float res = f[j] - q * s;
      float lq = rintf(res * rs * 256.0f);
      lq = fminf(fmaxf(lq, -127.f), 127.f);
      L.c[j] = (signed char)(int)lq;
    }
    signed char* dst = (isz ? z8 : c8) + (size_t)r * 512 + (d0 >> 6) * 128 + (d0 & 63);
    *(uint2*)dst        = H.u;
    *(uint2*)(dst + 64) = L.u;
    if ((t & 31) == 0) {
      if (isz) sz[r] = s;
      else { sc[r] = s; csq[r] = ssq; }
    }
  } else {
    float s = ema_cs[t] + ema_cs[t + 256] + ema_cs[t + 512] + ema_cs[t + 768];
#pragma unroll
    for (int off = 32; off; off >>= 1) s += __shfl_down(s, off);
    __shared__ float wsum[4];
    if ((t & 63) == 0) wsum[t >> 6] = s;
    __syncthreads();
    if (t == 0) S[0] = wsum[0] + wsum[1] + wsum[2] + wsum[3];
  }
}

// ---------------------------------------------------------------- i8 dist GEMM (R7 verbatim)
// 128x128 tile, 4 waves 2x2 (64x64 quadrant = 2x2 frags of 32x32), BK=64.
__global__ __launch_bounds__(256, 2) void dist_gemm_i8(
    const signed char* __restrict__ z8, const signed char* __restrict__ c8,
    const float* __restrict__ sz, const float* __restrict__ sc,
    const float* __restrict__ csq, float* __restrict__ dist) {
  __shared__ signed char lds[2][128 * 128];   // [A|B][row][64 h | 64 l] = 32 KB

  const int tid  = threadIdx.x;
  const int lane = tid & 63;
  const int w    = tid >> 6;

  const int bid = blockIdx.x;
  const int lin = (bid & 7) * 128 + (bid >> 3);   // XCD-bijective (1024 % 8 == 0)
  const int m0  = (lin >> 3) * 128;
  const int n0  = (lin & 7) * 128;

  const int wm0 = (w >> 1) * 64;
  const int wn0 = (w & 1) * 64;

  i32x16 accA[2][2];   // hh
  i32x16 accB[2][2];   // h*l + l*h  (both scaled 1/256)
#pragma unroll
  for (int i = 0; i < 2; ++i)
#pragma unroll
    for (int j = 0; j < 2; ++j) {
      accA[i][j] = (i32x16)(0);
      accB[i][j] = (i32x16)(0);
    }

  const int srow = lane >> 3;     // 8 rows per gload16 (128B/row)
  const int scb  = lane & 7;

  for (int kk = 0; kk < 4; ++kk) {
    __syncthreads();
#pragma unroll
    for (int j = 0; j < 4; ++j) {
      const int r0    = w * 32 + j * 8;
      const int row   = r0 + srow;
      const int chunk = scb ^ (row & 7);
      gload16(z8 + (size_t)(m0 + row) * 512 + kk * 128 + chunk * 16, &lds[0][r0 * 128]);
      gload16(c8 + (size_t)(n0 + row) * 512 + kk * 128 + chunk * 16, &lds[1][r0 * 128]);
    }
    __syncthreads();
#pragma unroll
    for (int s = 0; s < 2; ++s) {
      i32x4 ah[2], al[2], bh[2], bl[2];
      const int kc = s * 2 + (lane >> 5);        // h chunk 0..3; l = +4
#pragma unroll
      for (int fi = 0; fi < 2; ++fi) {
        const int ra = wm0 + fi * 32 + (lane & 31);
        ah[fi] = *(const i32x4*)&lds[0][ra * 128 + ((kc)     ^ (ra & 7)) * 16];
        al[fi] = *(const i32x4*)&lds[0][ra * 128 + ((kc + 4) ^ (ra & 7)) * 16];
        const int rb = wn0 + fi * 32 + (lane & 31);
        bh[fi] = *(const i32x4*)&lds[1][rb * 128 + ((kc)     ^ (rb & 7)) * 16];
        bl[fi] = *(const i32x4*)&lds[1][rb * 128 + ((kc + 4) ^ (rb & 7)) * 16];
      }
#pragma unroll
      for (int i = 0; i < 2; ++i)
#pragma unroll
        for (int j = 0; j < 2; ++j) {
          accA[i][j] = __builtin_amdgcn_mfma_i32_32x32x32_i8(ah[i], bh[j], accA[i][j], 0, 0, 0);
          accB[i][j] = __builtin_amdgcn_mfma_i32_32x32x32_i8(ah[i], bl[j], accB[i][j], 0, 0, 0);
          accB[i][j] = __builtin_amdgcn_mfma_i32_32x32x32_i8(al[i], bh[j], accB[i][j], 0, 0, 0);
        }
    }
  }

#pragma unroll
  for (int j = 0; j < 2; ++j) {
    const int colb = n0 + wn0 + j * 32 + (lane & 31);
    const float scv = sc[colb];
    const float cqv = csq[colb];
#pragma unroll
    for (int i = 0; i < 2; ++i) {
#pragma unroll
      for (int reg = 0; reg < 16; ++reg) {
        const int row = m0 + wm0 + i * 32 + (reg & 3) + 8 * (reg >> 2) + 4 * (lane >> 5);
        const float dotv = (float)accA[i][j][reg] + (float)accB[i][j][reg] * (1.0f / 256.0f);
        dist[(size_t)row * 1024 + colb] = cqv - 2.0f * sz[row] * scv * dotv;
      }
    }
  }
}

// ---------------------------------------------------------------- row softmax (no atomics)
// Block-per-row, 256 threads, float4 each. In-place dist->gamma; writes fIdx.
__global__ __launch_bounds__(256) void row_softmax(float* __restrict__ gamma,
                                                   int* __restrict__ fIdx,
                                                   int K) {
  const int n = blockIdx.x;
  const int t = threadIdx.x;
  float* row = gamma + (size_t)n * K;
  const float4 s = ((const float4*)row)[t];

  float mv = s.x; int mi = 4 * t;
  if (s.y < mv) { mv = s.y; mi = 4 * t + 1; }
  if (s.z < mv) { mv = s.z; mi = 4 * t + 2; }
  if (s.w < mv) { mv = s.w; mi = 4 * t + 3; }

#pragma unroll
  for (int off = 32; off; off >>= 1) {
    const float ov = __shfl_down(mv, off);
    const int   oi = __shfl_down(mi, off);
    if (ov < mv || (ov == mv && oi < mi)) { mv = ov; mi = oi; }
  }

  __shared__ float wv[4];
  __shared__ int   wi[4];
  __shared__ float fmin_s;
  __shared__ float fsum_s;
  const int wave = t >> 6;
  if ((t & 63) == 0) { wv[wave] = mv; wi[wave] = mi; }
  __syncthreads();
  if (t == 0) {
    float bv = wv[0]; int bi = wi[0];
#pragma unroll
    for (int wq = 1; wq < 4; ++wq)
      if (wv[wq] < bv || (wv[wq] == bv && wi[wq] < bi)) { bv = wv[wq]; bi = wi[wq]; }
    fmin_s = bv; fIdx[n] = bi;
  }
  __syncthreads();

  const float bm = fmin_s;
  const float e0 = __expf(-5.0f * (s.x - bm));
  const float e1 = __expf(-5.0f * (s.y - bm));
  const float e2 = __expf(-5.0f * (s.z - bm));
  const float e3 = __expf(-5.0f * (s.w - bm));
  float ls = e0 + e1 + e2 + e3;
#pragma unroll
  for (int off = 32; off; off >>= 1) ls += __shfl_down(ls, off);
  if ((t & 63) == 0) wv[wave] = ls;
  __syncthreads();
  if (t == 0) fsum_s = wv[0] + wv[1] + wv[2] + wv[3];
  __syncthreads();

  const float inv = 1.0f / fsum_s;
  float4 g;
  g.x = e0 * inv; g.y = e1 * inv; g.z = e2 * inv; g.w = e3 * inv;
  ((float4*)row)[t] = g;
}

// ---------------------------------------------------------------- dwfin (R10, no atomics)
// Block k: ballot-scan fIdx; for matching rows write recons[r]=cent[k] and
// accumulate z[r]; then outc[k] = (DECAY*ema_w[k] + OMD*dw) / newcs.
__global__ __launch_bounds__(256) void dwfin(const float* __restrict__ z,
                                             const float* __restrict__ cent,
                                             const float* __restrict__ ema_w,
                                             const float* __restrict__ ema_cs,
                                             const int* __restrict__ fIdx,
                                             const float* __restrict__ S,
                                             float* __restrict__ recons,
                                             float* __restrict__ outc,
                                             float fN, int N) {
  __shared__ float part[4][256];
  __shared__ int scnt[4];
  const int k    = blockIdx.x;
  const int w    = threadIdx.x >> 6;
  const int lane = threadIdx.x & 63;
  const int Q    = N >> 2;                         // rows per wave

  const float4 cv = *(const float4*)&cent[(size_t)k * 256 + lane * 4];

  float4 acc = {0.f, 0.f, 0.f, 0.f};
  int cnt = 0;
  const int base = w * Q;
  for (int c = 0; c < Q; c += 64) {
    const int fi = fIdx[base + c + lane];
    unsigned long long mask = __ballot(fi == k);
    cnt += __popcll(mask);
    while (mask) {
      const int b = __builtin_ctzll(mask);
      mask &= mask - 1;
      const int rr = base + c + b;
      const float4 zv = *(const float4*)&z[(size_t)rr * 256 + lane * 4];
      acc.x += zv.x; acc.y += zv.y; acc.z += zv.z; acc.w += zv.w;
      *(float4*)&recons[(size_t)rr * 256 + lane * 4] = cv;
    }
  }
  *(float4*)&part[w][lane * 4] = acc;
  if (lane == 0) scnt[w] = cnt;
  __syncthreads();
  if (w == 0) {
    const float4 a0 = *(const float4*)&part[0][lane * 4];
    const float4 a1 = *(const float4*)&part[1][lane * 4];
    const float4 a2 = *(const float4*)&part[2][lane * 4];
    const float4 a3 = *(const float4*)&part[3][lane * 4];
    float4 tot;
    tot.x = (a0.x + a1.x) + (a2.x + a3.x);
    tot.y = (a0.y + a1.y) + (a2.y + a3.y);
    tot.z = (a0.z + a1.z) + (a2.z + a3.z);
    tot.w = (a0.w + a1.w) + (a2.w + a3.w);
    const int  c   = (scnt[0] + scnt[1]) + (scnt[2] + scnt[3]);
    const float n  = DECAY * S[0] + OMD * fN;      // sum(new_cs): sum(counts)==N
    const float v  = DECAY * ema_cs[k] + OMD * (float)c;
    const float ncs = (v + EPSV) / (n + 1024.0f * EPSV) * n;
    const float rinv = 1.0f / ncs;
    const float4 w4 = *(const float4*)&ema_w[(size_t)k * 256 + lane * 4];
    float4 o;
    o.x = (DECAY * w4.x + OMD * tot.x) * rinv;
    o.y = (DECAY * w4.y + OMD * tot.y) * rinv;
    o.z = (DECAY * w4.z + OMD * tot.z) * rinv;
    o.w = (DECAY * w4.w + OMD * tot.w) * rinv;
    *(float4*)&outc[(size_t)k * 256 + lane * 4] = o;
  }
}

// ---------------------------------------------------------------- launch
extern "C" void kernel_launch(void* const* d_in, const int* in_sizes, int n_in,
                              void* d_out, int out_size, void* d_ws, size_t ws_size,
                              hipStream_t stream) {
  const float* z      = (const float*)d_in[0];
  const float* cent   = (const float*)d_in[1];
  const float* ema_w  = (const float*)d_in[2];
  const float* ema_cs = (const float*)d_in[3];

  const int K = in_sizes[3];            // 1024
  const int D = in_sizes[1] / K;        // 256
  const int N = in_sizes[0] / D;        // 16384

  float* out    = (float*)d_out;
  float* recons = out;                              // [N,D] = 16 MB
  float* gamma  = out + (size_t)N * D;              // [N,K] (dist, then gamma)
  float* outc   = gamma + (size_t)N * K;            // [K,D] = 1 MB

  // recons region scratch (dead before dwfin writes recons):
  signed char* z8 = (signed char*)recons;           // 8 MB

  // outc region scratch (outc written last by dwfin):
  signed char* c8 = (signed char*)outc;             // 512 KB
  float* sz = (float*)((char*)outc + (size_t)K * 512);  // N floats
  float* sc = sz + N;                               // K floats

  float* csq  = (float*)d_ws;                       // [K]
  float* S    = csq + K;                            // [1]
  int*   fIdx = (int*)(S + 1);                      // [N]

  prep<<<2177, 256, 0, stream>>>(z, cent, ema_cs, z8, c8, sz, sc, csq, S);

  dist_gemm_i8<<<(N / 128) * (K / 128), 256, 0, stream>>>(z8, c8, sz, sc, csq, gamma);

  row_softmax<<<N, 256, 0, stream>>>(gamma, fIdx, K);

  dwfin<<<K, 256, 0, stream>>>(z, cent, ema_w, ema_cs, fIdx, S, recons, outc,
                               (float)N, N);
}

// Round 12
// 113.119 us; speedup vs baseline: 2.5215x; 1.0918x over previous
//
#include <hip/hip_runtime.h>

// VectorQuantizerEMA: N=16384, K=1024, D=256.
// Outputs (f32, concat): recons [N,D] | gamma [N,K] | new_centroids [K,D]
// R12: R11 with dwfin's fIdx scan vectorized int4 (64 -> 16 latency-bound
// iterations per wave; 4 independent ballots per load). No other changes.

#define DECAY 0.95f
#define OMD   0.05f
#define EPSV  1e-5f

using i32x4  = __attribute__((ext_vector_type(4))) int;
using i32x16 = __attribute__((ext_vector_type(16))) int;

typedef __attribute__((address_space(3))) unsigned int       lds_uint;
typedef const __attribute__((address_space(1))) unsigned int glb_uint;

__device__ __forceinline__ void gload16(const void* g, const void* l) {
  __builtin_amdgcn_global_load_lds((glb_uint*)(unsigned long long)g,
                                   (lds_uint*)(unsigned int)(unsigned long long)l,
                                   16, 0, 0);
}

// ---------------------------------------------------------------- prep
// bid 0..2047    : z int8 hi/lo quantize (8 rows/block) + sz
// bid 2048..2175 : cent int8 quantize + sc + csq
// bid 2176       : S = sum(ema_cs)
__global__ __launch_bounds__(256) void prep(const float* __restrict__ z,
                                            const float* __restrict__ cent,
                                            const float* __restrict__ ema_cs,
                                            signed char* __restrict__ z8,
                                            signed char* __restrict__ c8,
                                            float* __restrict__ sz,
                                            float* __restrict__ sc,
                                            float* __restrict__ csq,
                                            float* __restrict__ S) {
  const int bid = blockIdx.x;
  const int t   = threadIdx.x;
  if (bid < 2176) {
    const bool isz = bid < 2048;
    const float* src = isz ? z : cent;
    const int rb = isz ? bid : (bid - 2048);
    const int r  = rb * 8 + (t >> 5);
    const int d0 = (t & 31) * 8;
    const float4 a = *(const float4*)&src[(size_t)r * 256 + d0];
    const float4 b = *(const float4*)&src[(size_t)r * 256 + d0 + 4];
    float f[8] = {a.x, a.y, a.z, a.w, b.x, b.y, b.z, b.w};
    float am = 0.f, ssq = 0.f;
#pragma unroll
    for (int j = 0; j < 8; ++j) { am = fmaxf(am, fabsf(f[j])); ssq += f[j] * f[j]; }
#pragma unroll
    for (int off = 16; off; off >>= 1) {
      am  = fmaxf(am, __shfl_down(am, off, 32));
      ssq += __shfl_down(ssq, off, 32);
    }
    am = __shfl(am, 0, 32);
    const float s  = fmaxf(am, 1e-6f) * (1.0f / 127.0f);
    const float rs = 1.0f / s;
    union { signed char c[8]; uint2 u; } H, L;
#pragma unroll
    for (int j = 0; j < 8; ++j) {
      float q = rintf(f[j] * rs);
      q = fminf(fmaxf(q, -127.f), 127.f);
      H.c[j] = (signed char)(int)q;
      float res = f[j] - q * s;
      float lq = rintf(res * rs * 256.0f);
      lq = fminf(fmaxf(lq, -127.f), 127.f);
      L.c[j] = (signed char)(int)lq;
    }
    signed char* dst = (isz ? z8 : c8) + (size_t)r * 512 + (d0 >> 6) * 128 + (d0 & 63);
    *(uint2*)dst        = H.u;
    *(uint2*)(dst + 64) = L.u;
    if ((t & 31) == 0) {
      if (isz) sz[r] = s;
      else { sc[r] = s; csq[r] = ssq; }
    }
  } else {
    float s = ema_cs[t] + ema_cs[t + 256] + ema_cs[t + 512] + ema_cs[t + 768];
#pragma unroll
    for (int off = 32; off; off >>= 1) s += __shfl_down(s, off);
    __shared__ float wsum[4];
    if ((t & 63) == 0) wsum[t >> 6] = s;
    __syncthreads();
    if (t == 0) S[0] = wsum[0] + wsum[1] + wsum[2] + wsum[3];
  }
}

// ---------------------------------------------------------------- i8 dist GEMM (R7 verbatim)
__global__ __launch_bounds__(256, 2) void dist_gemm_i8(
    const signed char* __restrict__ z8, const signed char* __restrict__ c8,
    const float* __restrict__ sz, const float* __restrict__ sc,
    const float* __restrict__ csq, float* __restrict__ dist) {
  __shared__ signed char lds[2][128 * 128];   // [A|B][row][64 h | 64 l] = 32 KB

  const int tid  = threadIdx.x;
  const int lane = tid & 63;
  const int w    = tid >> 6;

  const int bid = blockIdx.x;
  const int lin = (bid & 7) * 128 + (bid >> 3);   // XCD-bijective (1024 % 8 == 0)
  const int m0  = (lin >> 3) * 128;
  const int n0  = (lin & 7) * 128;

  const int wm0 = (w >> 1) * 64;
  const int wn0 = (w & 1) * 64;

  i32x16 accA[2][2];   // hh
  i32x16 accB[2][2];   // h*l + l*h  (both scaled 1/256)
#pragma unroll
  for (int i = 0; i < 2; ++i)
#pragma unroll
    for (int j = 0; j < 2; ++j) {
      accA[i][j] = (i32x16)(0);
      accB[i][j] = (i32x16)(0);
    }

  const int srow = lane >> 3;     // 8 rows per gload16 (128B/row)
  const int scb  = lane & 7;

  for (int kk = 0; kk < 4; ++kk) {
    __syncthreads();
#pragma unroll
    for (int j = 0; j < 4; ++j) {
      const int r0    = w * 32 + j * 8;
      const int row   = r0 + srow;
      const int chunk = scb ^ (row & 7);
      gload16(z8 + (size_t)(m0 + row) * 512 + kk * 128 + chunk * 16, &lds[0][r0 * 128]);
      gload16(c8 + (size_t)(n0 + row) * 512 + kk * 128 + chunk * 16, &lds[1][r0 * 128]);
    }
    __syncthreads();
#pragma unroll
    for (int s = 0; s < 2; ++s) {
      i32x4 ah[2], al[2], bh[2], bl[2];
      const int kc = s * 2 + (lane >> 5);        // h chunk 0..3; l = +4
#pragma unroll
      for (int fi = 0; fi < 2; ++fi) {
        const int ra = wm0 + fi * 32 + (lane & 31);
        ah[fi] = *(const i32x4*)&lds[0][ra * 128 + ((kc)     ^ (ra & 7)) * 16];
        al[fi] = *(const i32x4*)&lds[0][ra * 128 + ((kc + 4) ^ (ra & 7)) * 16];
        const int rb = wn0 + fi * 32 + (lane & 31);
        bh[fi] = *(const i32x4*)&lds[1][rb * 128 + ((kc)     ^ (rb & 7)) * 16];
        bl[fi] = *(const i32x4*)&lds[1][rb * 128 + ((kc + 4) ^ (rb & 7)) * 16];
      }
#pragma unroll
      for (int i = 0; i < 2; ++i)
#pragma unroll
        for (int j = 0; j < 2; ++j) {
          accA[i][j] = __builtin_amdgcn_mfma_i32_32x32x32_i8(ah[i], bh[j], accA[i][j], 0, 0, 0);
          accB[i][j] = __builtin_amdgcn_mfma_i32_32x32x32_i8(ah[i], bl[j], accB[i][j], 0, 0, 0);
          accB[i][j] = __builtin_amdgcn_mfma_i32_32x32x32_i8(al[i], bh[j], accB[i][j], 0, 0, 0);
        }
    }
  }

#pragma unroll
  for (int j = 0; j < 2; ++j) {
    const int colb = n0 + wn0 + j * 32 + (lane & 31);
    const float scv = sc[colb];
    const float cqv = csq[colb];
#pragma unroll
    for (int i = 0; i < 2; ++i) {
#pragma unroll
      for (int reg = 0; reg < 16; ++reg) {
        const int row = m0 + wm0 + i * 32 + (reg & 3) + 8 * (reg >> 2) + 4 * (lane >> 5);
        const float dotv = (float)accA[i][j][reg] + (float)accB[i][j][reg] * (1.0f / 256.0f);
        dist[(size_t)row * 1024 + colb] = cqv - 2.0f * sz[row] * scv * dotv;
      }
    }
  }
}

// ---------------------------------------------------------------- row softmax (no atomics)
__global__ __launch_bounds__(256) void row_softmax(float* __restrict__ gamma,
                                                   int* __restrict__ fIdx,
                                                   int K) {
  const int n = blockIdx.x;
  const int t = threadIdx.x;
  float* row = gamma + (size_t)n * K;
  const float4 s = ((const float4*)row)[t];

  float mv = s.x; int mi = 4 * t;
  if (s.y < mv) { mv = s.y; mi = 4 * t + 1; }
  if (s.z < mv) { mv = s.z; mi = 4 * t + 2; }
  if (s.w < mv) { mv = s.w; mi = 4 * t + 3; }

#pragma unroll
  for (int off = 32; off; off >>= 1) {
    const float ov = __shfl_down(mv, off);
    const int   oi = __shfl_down(mi, off);
    if (ov < mv || (ov == mv && oi < mi)) { mv = ov; mi = oi; }
  }

  __shared__ float wv[4];
  __shared__ int   wi[4];
  __shared__ float fmin_s;
  __shared__ float fsum_s;
  const int wave = t >> 6;
  if ((t & 63) == 0) { wv[wave] = mv; wi[wave] = mi; }
  __syncthreads();
  if (t == 0) {
    float bv = wv[0]; int bi = wi[0];
#pragma unroll
    for (int wq = 1; wq < 4; ++wq)
      if (wv[wq] < bv || (wv[wq] == bv && wi[wq] < bi)) { bv = wv[wq]; bi = wi[wq]; }
    fmin_s = bv; fIdx[n] = bi;
  }
  __syncthreads();

  const float bm = fmin_s;
  const float e0 = __expf(-5.0f * (s.x - bm));
  const float e1 = __expf(-5.0f * (s.y - bm));
  const float e2 = __expf(-5.0f * (s.z - bm));
  const float e3 = __expf(-5.0f * (s.w - bm));
  float ls = e0 + e1 + e2 + e3;
#pragma unroll
  for (int off = 32; off; off >>= 1) ls += __shfl_down(ls, off);
  if ((t & 63) == 0) wv[wave] = ls;
  __syncthreads();
  if (t == 0) fsum_s = wv[0] + wv[1] + wv[2] + wv[3];
  __syncthreads();

  const float inv = 1.0f / fsum_s;
  float4 g;
  g.x = e0 * inv; g.y = e1 * inv; g.z = e2 * inv; g.w = e3 * inv;
  ((float4*)row)[t] = g;
}

// ---------------------------------------------------------------- dwfin (int4 scan)
// Block k: int4 ballot-scan of fIdx (16 iters/wave); matching rows get
// recons[r]=cent[k] and z[r] accumulated; inline EMA finalize. No atomics.
__global__ __launch_bounds__(256) void dwfin(const float* __restrict__ z,
                                             const float* __restrict__ cent,
                                             const float* __restrict__ ema_w,
                                             const float* __restrict__ ema_cs,
                                             const int* __restrict__ fIdx,
                                             const float* __restrict__ S,
                                             float* __restrict__ recons,
                                             float* __restrict__ outc,
                                             float fN, int N) {
  __shared__ float part[4][256];
  __shared__ int scnt[4];
  const int k    = blockIdx.x;
  const int w    = threadIdx.x >> 6;
  const int lane = threadIdx.x & 63;
  const int Q    = N >> 2;                         // rows per wave (4096)

  const float4 cv = *(const float4*)&cent[(size_t)k * 256 + lane * 4];

  float4 acc = {0.f, 0.f, 0.f, 0.f};
  int cnt = 0;
  const int base = w * Q;
  for (int c = 0; c < Q; c += 256) {               // 16 iterations
    const int4 fi = *(const int4*)&fIdx[base + c + lane * 4];
    unsigned long long m[4];
    m[0] = __ballot(fi.x == k);
    m[1] = __ballot(fi.y == k);
    m[2] = __ballot(fi.z == k);
    m[3] = __ballot(fi.w == k);
    cnt += __popcll(m[0]) + __popcll(m[1]) + __popcll(m[2]) + __popcll(m[3]);
#pragma unroll
    for (int q = 0; q < 4; ++q) {
      unsigned long long mask = m[q];
      while (mask) {
        const int b = __builtin_ctzll(mask);
        mask &= mask - 1;
        const int rr = base + c + b * 4 + q;
        const float4 zv = *(const float4*)&z[(size_t)rr * 256 + lane * 4];
        acc.x += zv.x; acc.y += zv.y; acc.z += zv.z; acc.w += zv.w;
        *(float4*)&recons[(size_t)rr * 256 + lane * 4] = cv;
      }
    }
  }
  *(float4*)&part[w][lane * 4] = acc;
  if (lane == 0) scnt[w] = cnt;
  __syncthreads();
  if (w == 0) {
    const float4 a0 = *(const float4*)&part[0][lane * 4];
    const float4 a1 = *(const float4*)&part[1][lane * 4];
    const float4 a2 = *(const float4*)&part[2][lane * 4];
    const float4 a3 = *(const float4*)&part[3][lane * 4];
    float4 tot;
    tot.x = (a0.x + a1.x) + (a2.x + a3.x);
    tot.y = (a0.y + a1.y) + (a2.y + a3.y);
    tot.z = (a0.z + a1.z) + (a2.z + a3.z);
    tot.w = (a0.w + a1.w) + (a2.w + a3.w);
    const int  c   = (scnt[0] + scnt[1]) + (scnt[2] + scnt[3]);
    const float n  = DECAY * S[0] + OMD * fN;      // sum(new_cs): sum(counts)==N
    const float v  = DECAY * ema_cs[k] + OMD * (float)c;
    const float ncs = (v + EPSV) / (n + 1024.0f * EPSV) * n;
    const float rinv = 1.0f / ncs;
    const float4 w4 = *(const float4*)&ema_w[(size_t)k * 256 + lane * 4];
    float4 o;
    o.x = (DECAY * w4.x + OMD * tot.x) * rinv;
    o.y = (DECAY * w4.y + OMD * tot.y) * rinv;
    o.z = (DECAY * w4.z + OMD * tot.z) * rinv;
    o.w = (DECAY * w4.w + OMD * tot.w) * rinv;
    *(float4*)&outc[(size_t)k * 256 + lane * 4] = o;
  }
}

// ---------------------------------------------------------------- launch
extern "C" void kernel_launch(void* const* d_in, const int* in_sizes, int n_in,
                              void* d_out, int out_size, void* d_ws, size_t ws_size,
                              hipStream_t stream) {
  const float* z      = (const float*)d_in[0];
  const float* cent   = (const float*)d_in[1];
  const float* ema_w  = (const float*)d_in[2];
  const float* ema_cs = (const float*)d_in[3];

  const int K = in_sizes[3];            // 1024
  const int D = in_sizes[1] / K;        // 256
  const int N = in_sizes[0] / D;        // 16384

  float* out    = (float*)d_out;
  float* recons = out;                              // [N,D] = 16 MB
  float* gamma  = out + (size_t)N * D;              // [N,K] (dist, then gamma)
  float* outc   = gamma + (size_t)N * K;            // [K,D] = 1 MB

  // recons region scratch (dead before dwfin writes recons):
  signed char* z8 = (signed char*)recons;           // 8 MB

  // outc region scratch (outc written last by dwfin):
  signed char* c8 = (signed char*)outc;             // 512 KB
  float* sz = (float*)((char*)outc + (size_t)K * 512);  // N floats
  float* sc = sz + N;                               // K floats

  float* csq  = (float*)d_ws;                       // [K]
  float* S    = csq + K;                            // [1]
  int*   fIdx = (int*)(S + 1);                      // [N]

  prep<<<2177, 256, 0, stream>>>(z, cent, ema_cs, z8, c8, sz, sc, csq, S);

  dist_gemm_i8<<<(N / 128) * (K / 128), 256, 0, stream>>>(z8, c8, sz, sc, csq, gamma);

  row_softmax<<<N, 256, 0, stream>>>(gamma, fIdx, K);

  dwfin<<<K, 256, 0, stream>>>(z, cent, ema_w, ema_cs, fIdx, S, recons, outc,
                               (float)N, N);
}

// Round 14
// 81.326 us; speedup vs baseline: 3.5072x; 1.3909x over previous
//
#include <hip/hip_runtime.h>

// VectorQuantizerEMA: N=16384, K=1024, D=256.
// Outputs (f32, concat): recons [N,D] | gamma [N,K] | new_centroids [K,D]
// R14 (= R13 + compile fix): dw segment-sum split 32-way (K x 4 slice-blocks
// x 8 waves) -> per-slice partials; reduce_fin folds + EMA; recons_fill
// gathers recons afterwards (dwp parks in recons region behind dead z8).

#define DECAY 0.95f
#define OMD   0.05f
#define EPSV  1e-5f

using i32x4  = __attribute__((ext_vector_type(4))) int;
using i32x16 = __attribute__((ext_vector_type(16))) int;

typedef __attribute__((address_space(3))) unsigned int       lds_uint;
typedef const __attribute__((address_space(1))) unsigned int glb_uint;

__device__ __forceinline__ void gload16(const void* g, const void* l) {
  __builtin_amdgcn_global_load_lds((glb_uint*)(unsigned long long)g,
                                   (lds_uint*)(unsigned int)(unsigned long long)l,
                                   16, 0, 0);
}

// ---------------------------------------------------------------- prep
// bid 0..2047    : z int8 hi/lo quantize (8 rows/block) + sz
// bid 2048..2175 : cent int8 quantize + sc + csq
// bid 2176       : S = sum(ema_cs)
__global__ __launch_bounds__(256) void prep(const float* __restrict__ z,
                                            const float* __restrict__ cent,
                                            const float* __restrict__ ema_cs,
                                            signed char* __restrict__ z8,
                                            signed char* __restrict__ c8,
                                            float* __restrict__ sz,
                                            float* __restrict__ sc,
                                            float* __restrict__ csq,
                                            float* __restrict__ S) {
  const int bid = blockIdx.x;
  const int t   = threadIdx.x;
  if (bid < 2176) {
    const bool isz = bid < 2048;
    const float* src = isz ? z : cent;
    const int rb = isz ? bid : (bid - 2048);
    const int r  = rb * 8 + (t >> 5);
    const int d0 = (t & 31) * 8;
    const float4 a = *(const float4*)&src[(size_t)r * 256 + d0];
    const float4 b = *(const float4*)&src[(size_t)r * 256 + d0 + 4];
    float f[8] = {a.x, a.y, a.z, a.w, b.x, b.y, b.z, b.w};
    float am = 0.f, ssq = 0.f;
#pragma unroll
    for (int j = 0; j < 8; ++j) { am = fmaxf(am, fabsf(f[j])); ssq += f[j] * f[j]; }
#pragma unroll
    for (int off = 16; off; off >>= 1) {
      am  = fmaxf(am, __shfl_down(am, off, 32));
      ssq += __shfl_down(ssq, off, 32);
    }
    am = __shfl(am, 0, 32);
    const float s  = fmaxf(am, 1e-6f) * (1.0f / 127.0f);
    const float rs = 1.0f / s;
    union { signed char c[8]; uint2 u; } H, L;
#pragma unroll
    for (int j = 0; j < 8; ++j) {
      float q = rintf(f[j] * rs);
      q = fminf(fmaxf(q, -127.f), 127.f);
      H.c[j] = (signed char)(int)q;
      float res = f[j] - q * s;
      float lq = rintf(res * rs * 256.0f);
      lq = fminf(fmaxf(lq, -127.f), 127.f);
      L.c[j] = (signed char)(int)lq;
    }
    signed char* dst = (isz ? z8 : c8) + (size_t)r * 512 + (d0 >> 6) * 128 + (d0 & 63);
    *(uint2*)dst        = H.u;
    *(uint2*)(dst + 64) = L.u;
    if ((t & 31) == 0) {
      if (isz) sz[r] = s;
      else { sc[r] = s; csq[r] = ssq; }
    }
  } else {
    float s = ema_cs[t] + ema_cs[t + 256] + ema_cs[t + 512] + ema_cs[t + 768];
#pragma unroll
    for (int off = 32; off; off >>= 1) s += __shfl_down(s, off);
    __shared__ float wsum[4];
    if ((t & 63) == 0) wsum[t >> 6] = s;
    __syncthreads();
    if (t == 0) S[0] = wsum[0] + wsum[1] + wsum[2] + wsum[3];
  }
}

// ---------------------------------------------------------------- i8 dist GEMM (R7 verbatim)
__global__ __launch_bounds__(256, 2) void dist_gemm_i8(
    const signed char* __restrict__ z8, const signed char* __restrict__ c8,
    const float* __restrict__ sz, const float* __restrict__ sc,
    const float* __restrict__ csq, float* __restrict__ dist) {
  __shared__ signed char lds[2][128 * 128];   // [A|B][row][64 h | 64 l] = 32 KB

  const int tid  = threadIdx.x;
  const int lane = tid & 63;
  const int w    = tid >> 6;

  const int bid = blockIdx.x;
  const int lin = (bid & 7) * 128 + (bid >> 3);   // XCD-bijective (1024 % 8 == 0)
  const int m0  = (lin >> 3) * 128;
  const int n0  = (lin & 7) * 128;

  const int wm0 = (w >> 1) * 64;
  const int wn0 = (w & 1) * 64;

  i32x16 accA[2][2];   // hh
  i32x16 accB[2][2];   // h*l + l*h  (both scaled 1/256)
#pragma unroll
  for (int i = 0; i < 2; ++i)
#pragma unroll
    for (int j = 0; j < 2; ++j) {
      accA[i][j] = (i32x16)(0);
      accB[i][j] = (i32x16)(0);
    }

  const int srow = lane >> 3;     // 8 rows per gload16 (128B/row)
  const int scb  = lane & 7;

  for (int kk = 0; kk < 4; ++kk) {
    __syncthreads();
#pragma unroll
    for (int j = 0; j < 4; ++j) {
      const int r0    = w * 32 + j * 8;
      const int row   = r0 + srow;
      const int chunk = scb ^ (row & 7);
      gload16(z8 + (size_t)(m0 + row) * 512 + kk * 128 + chunk * 16, &lds[0][r0 * 128]);
      gload16(c8 + (size_t)(n0 + row) * 512 + kk * 128 + chunk * 16, &lds[1][r0 * 128]);
    }
    __syncthreads();
#pragma unroll
    for (int s = 0; s < 2; ++s) {
      i32x4 ah[2], al[2], bh[2], bl[2];
      const int kc = s * 2 + (lane >> 5);        // h chunk 0..3; l = +4
#pragma unroll
      for (int fi = 0; fi < 2; ++fi) {
        const int ra = wm0 + fi * 32 + (lane & 31);
        ah[fi] = *(const i32x4*)&lds[0][ra * 128 + ((kc)     ^ (ra & 7)) * 16];
        al[fi] = *(const i32x4*)&lds[0][ra * 128 + ((kc + 4) ^ (ra & 7)) * 16];
        const int rb = wn0 + fi * 32 + (lane & 31);
        bh[fi] = *(const i32x4*)&lds[1][rb * 128 + ((kc)     ^ (rb & 7)) * 16];
        bl[fi] = *(const i32x4*)&lds[1][rb * 128 + ((kc + 4) ^ (rb & 7)) * 16];
      }
#pragma unroll
      for (int i = 0; i < 2; ++i)
#pragma unroll
        for (int j = 0; j < 2; ++j) {
          accA[i][j] = __builtin_amdgcn_mfma_i32_32x32x32_i8(ah[i], bh[j], accA[i][j], 0, 0, 0);
          accB[i][j] = __builtin_amdgcn_mfma_i32_32x32x32_i8(ah[i], bl[j], accB[i][j], 0, 0, 0);
          accB[i][j] = __builtin_amdgcn_mfma_i32_32x32x32_i8(al[i], bh[j], accB[i][j], 0, 0, 0);
        }
    }
  }

#pragma unroll
  for (int j = 0; j < 2; ++j) {
    const int colb = n0 + wn0 + j * 32 + (lane & 31);
    const float scv = sc[colb];
    const float cqv = csq[colb];
#pragma unroll
    for (int i = 0; i < 2; ++i) {
#pragma unroll
      for (int reg = 0; reg < 16; ++reg) {
        const int row = m0 + wm0 + i * 32 + (reg & 3) + 8 * (reg >> 2) + 4 * (lane >> 5);
        const float dotv = (float)accA[i][j][reg] + (float)accB[i][j][reg] * (1.0f / 256.0f);
        dist[(size_t)row * 1024 + colb] = cqv - 2.0f * sz[row] * scv * dotv;
      }
    }
  }
}

// ---------------------------------------------------------------- row softmax (no atomics)
__global__ __launch_bounds__(256) void row_softmax(float* __restrict__ gamma,
                                                   int* __restrict__ fIdx,
                                                   int K) {
  const int n = blockIdx.x;
  const int t = threadIdx.x;
  float* row = gamma + (size_t)n * K;
  const float4 s = ((const float4*)row)[t];

  float mv = s.x; int mi = 4 * t;
  if (s.y < mv) { mv = s.y; mi = 4 * t + 1; }
  if (s.z < mv) { mv = s.z; mi = 4 * t + 2; }
  if (s.w < mv) { mv = s.w; mi = 4 * t + 3; }

#pragma unroll
  for (int off = 32; off; off >>= 1) {
    const float ov = __shfl_down(mv, off);
    const int   oi = __shfl_down(mi, off);
    if (ov < mv || (ov == mv && oi < mi)) { mv = ov; mi = oi; }
  }

  __shared__ float wv[4];
  __shared__ int   wi[4];
  __shared__ float fmin_s;
  __shared__ float fsum_s;
  const int wave = t >> 6;
  if ((t & 63) == 0) { wv[wave] = mv; wi[wave] = mi; }
  __syncthreads();
  if (t == 0) {
    float bv = wv[0]; int bi = wi[0];
#pragma unroll
    for (int wq = 1; wq < 4; ++wq)
      if (wv[wq] < bv || (wv[wq] == bv && wi[wq] < bi)) { bv = wv[wq]; bi = wi[wq]; }
    fmin_s = bv; fIdx[n] = bi;
  }
  __syncthreads();

  const float bm = fmin_s;
  const float e0 = __expf(-5.0f * (s.x - bm));
  const float e1 = __expf(-5.0f * (s.y - bm));
  const float e2 = __expf(-5.0f * (s.z - bm));
  const float e3 = __expf(-5.0f * (s.w - bm));
  float ls = e0 + e1 + e2 + e3;
#pragma unroll
  for (int off = 32; off; off >>= 1) ls += __shfl_down(ls, off);
  if ((t & 63) == 0) wv[wave] = ls;
  __syncthreads();
  if (t == 0) fsum_s = wv[0] + wv[1] + wv[2] + wv[3];
  __syncthreads();

  const float inv = 1.0f / fsum_s;
  float4 g;
  g.x = e0 * inv; g.y = e1 * inv; g.z = e2 * inv; g.w = e3 * inv;
  ((float4*)row)[t] = g;
}

// ---------------------------------------------------------------- dw_scan
// Block b: centroid k=b>>2, row-slice s=b&3 (4096 rows). 8 waves x 512 rows.
// Writes per-slice partial sums dwp[b][256] + counts cntp[b]. No recons here.
__global__ __launch_bounds__(512) void dw_scan(const float* __restrict__ z,
                                               const int* __restrict__ fIdx,
                                               float* __restrict__ dwp,
                                               int* __restrict__ cntp) {
  __shared__ float part[8][256];
  __shared__ int scnt[8];
  const int k    = blockIdx.x >> 2;
  const int s    = blockIdx.x & 3;
  const int ww   = threadIdx.x >> 6;
  const int lane = threadIdx.x & 63;

  float4 acc0 = {0.f, 0.f, 0.f, 0.f};
  float4 acc1 = {0.f, 0.f, 0.f, 0.f};
  int cnt = 0;
  const int base = s * 4096 + ww * 512;
  for (int c = 0; c < 512; c += 256) {             // 2 iterations
    const int4 fi = *(const int4*)&fIdx[base + c + lane * 4];
    unsigned long long m[4];
    m[0] = __ballot(fi.x == k);
    m[1] = __ballot(fi.y == k);
    m[2] = __ballot(fi.z == k);
    m[3] = __ballot(fi.w == k);
    cnt += __popcll(m[0]) + __popcll(m[1]) + __popcll(m[2]) + __popcll(m[3]);
#pragma unroll
    for (int q = 0; q < 4; q += 2) {               // 2-chain ILP drain
      unsigned long long ma = m[q], mb = m[q + 1];
      while (ma | mb) {
        if (ma) {
          const int b = __builtin_ctzll(ma); ma &= ma - 1;
          const int rr = base + c + b * 4 + q;
          const float4 zv = *(const float4*)&z[(size_t)rr * 256 + lane * 4];
          acc0.x += zv.x; acc0.y += zv.y; acc0.z += zv.z; acc0.w += zv.w;
        }
        if (mb) {
          const int b = __builtin_ctzll(mb); mb &= mb - 1;
          const int rr = base + c + b * 4 + q + 1;
          const float4 zv = *(const float4*)&z[(size_t)rr * 256 + lane * 4];
          acc1.x += zv.x; acc1.y += zv.y; acc1.z += zv.z; acc1.w += zv.w;
        }
      }
    }
  }
  acc0.x += acc1.x; acc0.y += acc1.y; acc0.z += acc1.z; acc0.w += acc1.w;
  *(float4*)&part[ww][lane * 4] = acc0;
  if (lane == 0) scnt[ww] = cnt;
  __syncthreads();
  if (ww == 0) {
    float4 tot = {0.f, 0.f, 0.f, 0.f};
    int c = 0;
#pragma unroll
    for (int e = 0; e < 8; ++e) {
      const float4 p = *(const float4*)&part[e][lane * 4];
      tot.x += p.x; tot.y += p.y; tot.z += p.z; tot.w += p.w;
      c += scnt[e];
    }
    *(float4*)&dwp[(size_t)blockIdx.x * 256 + lane * 4] = tot;
    if (lane == 0) cntp[blockIdx.x] = c;
  }
}

// ---------------------------------------------------------------- reduce_fin
__global__ __launch_bounds__(256) void reduce_fin(const float* __restrict__ dwp,
                                                  const int* __restrict__ cntp,
                                                  const float* __restrict__ ema_w,
                                                  const float* __restrict__ ema_cs,
                                                  const float* __restrict__ S,
                                                  float* __restrict__ outc,
                                                  float fN) {
  const int k = blockIdx.x;
  const int t = threadIdx.x;
  const size_t b0 = (size_t)k * 4 * 256 + t;
  const float dsum = (dwp[b0] + dwp[b0 + 256]) + (dwp[b0 + 512] + dwp[b0 + 768]);
  const int   c    = (cntp[k * 4] + cntp[k * 4 + 1]) + (cntp[k * 4 + 2] + cntp[k * 4 + 3]);
  const float n   = DECAY * S[0] + OMD * fN;       // sum(new_cs): sum(counts)==N
  const float v   = DECAY * ema_cs[k] + OMD * (float)c;
  const float ncs = (v + EPSV) / (n + 1024.0f * EPSV) * n;
  const size_t i  = (size_t)k * 256 + t;
  outc[i] = (DECAY * ema_w[i] + OMD * dsum) / ncs;
}

// ---------------------------------------------------------------- recons_fill
__global__ __launch_bounds__(256) void recons_fill(const float* __restrict__ cent,
                                                   const int* __restrict__ fIdx,
                                                   float* __restrict__ recons) {
  const int r    = blockIdx.x * 4 + (threadIdx.x >> 6);
  const int lane = threadIdx.x & 63;
  const int idx  = fIdx[r];
  *(float4*)&recons[(size_t)r * 256 + lane * 4] =
      *(const float4*)&cent[(size_t)idx * 256 + lane * 4];
}

// ---------------------------------------------------------------- launch
extern "C" void kernel_launch(void* const* d_in, const int* in_sizes, int n_in,
                              void* d_out, int out_size, void* d_ws, size_t ws_size,
                              hipStream_t stream) {
  const float* z      = (const float*)d_in[0];
  const float* cent   = (const float*)d_in[1];
  const float* ema_w  = (const float*)d_in[2];
  const float* ema_cs = (const float*)d_in[3];

  const int K = in_sizes[3];            // 1024
  const int D = in_sizes[1] / K;        // 256
  const int N = in_sizes[0] / D;        // 16384

  float* out    = (float*)d_out;
  float* recons = out;                              // [N,D] = 16 MB
  float* gamma  = out + (size_t)N * D;              // [N,K] (dist, then gamma)
  float* outc   = gamma + (size_t)N * K;            // [K,D] = 1 MB

  // recons region scratch (all dead before recons_fill writes recons):
  signed char* z8 = (signed char*)recons;                         // [0, 8MB)
  float* dwp  = (float*)((char*)recons + ((size_t)8 << 20));      // [8MB, 12MB)
  int*   cntp = (int*)((char*)recons + ((size_t)12 << 20));       // 16 KB

  // outc region scratch (outc written last by reduce_fin):
  signed char* c8 = (signed char*)outc;             // 512 KB
  float* sz = (float*)((char*)outc + (size_t)K * 512);  // N floats
  float* sc = sz + N;                               // K floats

  float* csq  = (float*)d_ws;                       // [K]
  float* S    = csq + K;                            // [1]
  int*   fIdx = (int*)(S + 1);                      // [N]

  prep<<<2177, 256, 0, stream>>>(z, cent, ema_cs, z8, c8, sz, sc, csq, S);

  dist_gemm_i8<<<(N / 128) * (K / 128), 256, 0, stream>>>(z8, c8, sz, sc, csq, gamma);

  row_softmax<<<N, 256, 0, stream>>>(gamma, fIdx, K);

  dw_scan<<<K * 4, 512, 0, stream>>>(z, fIdx, dwp, cntp);

  reduce_fin<<<K, 256, 0, stream>>>(dwp, cntp, ema_w, ema_cs, S, outc, (float)N);

  recons_fill<<<N / 4, 256, 0, stream>>>(cent, fIdx, recons);
}